// Round 6
// baseline (366.326 us; speedup 1.0000x reference)
//
#include <hip/hip_runtime.h>
#include <math.h>

#define N_NODES 100000
#define N_EDGES 1600000
#define D_IN 256
#define N_HEADS 4
#define D_OUT 32
#define D_HID 128   // N_HEADS*D_OUT
#define NEG_SLOPE 0.2f

// bucketed sort params
#define BUCKET_SHIFT 8
#define BUCKET_NODES 256
#define NB ((N_NODES + BUCKET_NODES - 1) / BUCKET_NODES)  // 391
#define CAP 6144      // >> mean 4096 + 32 sigma
#define TILE 2048
#define EPT 8         // edges per thread in k_bucket
#define N_TILES ((N_EDGES + TILE - 1) / TILE)             // 782

typedef __attribute__((ext_vector_type(8))) short bf16x8;
typedef __attribute__((ext_vector_type(4))) float f32x4;

// hardware packed f32->bf16 (RNE), 1 inst per 2 elements
static __device__ __forceinline__ unsigned cvt2(float lo, float hi) {
  unsigned r;
  asm("v_cvt_pk_bf16_f32 %0, %1, %2" : "=v"(r) : "v"(lo), "v"(hi));
  return r;
}
static __device__ __forceinline__ float bfu_lo(unsigned u) {
  union { unsigned u; float f; } c; c.u = u << 16; return c.f;
}
static __device__ __forceinline__ float bfu_hi(unsigned u) {
  union { unsigned u; float f; } c; c.u = u & 0xFFFF0000u; return c.f;
}

// ---------------- w f32 -> bf16 pre-convert (64 KB, L2-resident) -----------
__global__ __launch_bounds__(256) void k_wcvt(const float* __restrict__ w,
                                              unsigned short* __restrict__ wb) {
  int i = blockIdx.x * 256 + threadIdx.x;   // float4 group index
  if (i < (D_HID * D_IN) / 4) {
    float4 v = ((const float4*)w)[i];
    ((uint2*)wb)[i] = make_uint2(cvt2(v.x, v.y), cvt2(v.z, v.w));
  }
}

// ---------------- GEMM: ftb[N,128](bf16) = x[N,256] @ w[128,256]^T ----------
// One-shot staging: whole 128-row A slab (f32->bf16 in regs) + whole W (bf16)
// into 128 KiB LDS with XOR swizzle ((row&7)<<4), ONE barrier, then a
// barrier-free fully-unrolled MFMA sweep. Fused el/er epilogue from f32 acc.
__global__ __launch_bounds__(256, 1) void k_gemm(const float* __restrict__ x,
                                                 const unsigned short* __restrict__ wb,
                                                 const float* __restrict__ al,
                                                 const float* __restrict__ ar,
                                                 unsigned short* __restrict__ ftb,
                                                 float* __restrict__ el,
                                                 float* __restrict__ er) {
  __shared__ char lds[131072];
  char* As = lds;              // 128 rows x 512 B (256 bf16), swizzled
  char* Ws = lds + 65536;      // 128 cols x 512 B (256 bf16), swizzled
  int t = threadIdx.x;
  int wave = t >> 6, lane = t & 63;
  int quad = lane >> 4, l16 = lane & 15;
  int rowBlk = blockIdx.x * 128;

  // ---- stage: 2 threads per row; 32 x-float4 + 16 wb-uint4 loads/thread ----
  {
    int r = t >> 1, h = t & 1;
    int grow = rowBlk + r;
    bool v = grow < N_NODES;
    const float* xp = x + (size_t)(v ? grow : 0) * D_IN + h * 128;
    unsigned swz = (unsigned)((r & 7) << 4);
    char* abase = As + r * 512 + h * 256;
    char* wbase = Ws + r * 512 + h * 256;
    const uint4* wp = (const uint4*)wb + t * 16;
    const float4 z4 = make_float4(0.f, 0.f, 0.f, 0.f);
    #pragma unroll
    for (int c = 0; c < 16; ++c) {
      float4 v0 = v ? *(const float4*)(xp + c * 8) : z4;
      float4 v1 = v ? *(const float4*)(xp + c * 8 + 4) : z4;
      uint4 wv = wp[c];
      uint4 av = make_uint4(cvt2(v0.x, v0.y), cvt2(v0.z, v0.w),
                            cvt2(v1.x, v1.y), cvt2(v1.z, v1.w));
      *(uint4*)(abase + ((unsigned)(c * 16) ^ swz)) = av;
      *(uint4*)(wbase + ((unsigned)(c * 16) ^ swz)) = wv;
    }
  }
  __syncthreads();

  // ---- compute: wave owns 32 rows x 128 cols; acc[2][8]; no barriers ----
  f32x4 acc[2][8];
  #pragma unroll
  for (int mt = 0; mt < 2; ++mt)
    #pragma unroll
    for (int nt = 0; nt < 8; ++nt) {
      acc[mt][nt][0] = 0.f; acc[mt][nt][1] = 0.f;
      acc[mt][nt][2] = 0.f; acc[mt][nt][3] = 0.f;
    }
  unsigned swzL = (unsigned)((l16 & 7) << 4);
  int m0 = wave * 32 + l16;
  #pragma unroll
  for (int kb = 0; kb < 8; ++kb) {
    unsigned ko = (unsigned)(kb * 64 + quad * 16);
    bf16x8 a0 = *(const bf16x8*)(As + m0 * 512 + (ko ^ swzL));
    bf16x8 a1 = *(const bf16x8*)(As + (m0 + 16) * 512 + (ko ^ swzL));
    bf16x8 b[8];
    #pragma unroll
    for (int nt = 0; nt < 8; ++nt)
      b[nt] = *(const bf16x8*)(Ws + (nt * 16 + l16) * 512 + (ko ^ swzL));
    #pragma unroll
    for (int nt = 0; nt < 8; ++nt) {
      acc[0][nt] = __builtin_amdgcn_mfma_f32_16x16x32_bf16(a0, b[nt], acc[0][nt], 0, 0, 0);
      acc[1][nt] = __builtin_amdgcn_mfma_f32_16x16x32_bf16(a1, b[nt], acc[1][nt], 0, 0, 0);
    }
  }

  int rowBase = rowBlk + wave * 32;

  // ftb store (bf16)
  #pragma unroll
  for (int mt = 0; mt < 2; ++mt) {
    #pragma unroll
    for (int nt = 0; nt < 8; ++nt) {
      int col = nt * 16 + l16;
      #pragma unroll
      for (int r = 0; r < 4; r += 2) {
        unsigned p = cvt2(acc[mt][nt][r], acc[mt][nt][r + 1]);
        int row = rowBase + mt * 16 + quad * 4 + r;
        if (row < N_NODES)
          ftb[(size_t)row * D_HID + col] = (unsigned short)p;
        if (row + 1 < N_NODES)
          ftb[(size_t)(row + 1) * D_HID + col] = (unsigned short)(p >> 16);
      }
    }
  }

  // fused el/er from f32 accumulators: head h covers nt {2h, 2h+1};
  // reduce over the 16 lanes of the quad.
  float alf[8], arf[8];
  #pragma unroll
  for (int nt = 0; nt < 8; ++nt) {
    alf[nt] = al[nt * 16 + l16];
    arf[nt] = ar[nt * 16 + l16];
  }
  #pragma unroll
  for (int mt = 0; mt < 2; ++mt) {
    #pragma unroll
    for (int r = 0; r < 4; ++r) {
      int row = rowBase + mt * 16 + quad * 4 + r;
      float sl[4], sr[4];
      #pragma unroll
      for (int h = 0; h < 4; ++h) {
        sl[h] = acc[mt][2 * h][r] * alf[2 * h] + acc[mt][2 * h + 1][r] * alf[2 * h + 1];
        sr[h] = acc[mt][2 * h][r] * arf[2 * h] + acc[mt][2 * h + 1][r] * arf[2 * h + 1];
      }
      #pragma unroll
      for (int o = 1; o < 16; o <<= 1) {
        #pragma unroll
        for (int h = 0; h < 4; ++h) {
          sl[h] += __shfl_xor(sl[h], o);
          sr[h] += __shfl_xor(sr[h], o);
        }
      }
      if (l16 == 0 && row < N_NODES) {
        *(float4*)&el[row * 4] = make_float4(sl[0], sl[1], sl[2], sl[3]);
        *(float4*)&er[row * 4] = make_float4(sr[0], sr[1], sr[2], sr[3]);
      }
    }
  }
}

// ---------------- phase 1: bucket edges by dst>>8, packed (src<<8)|dlocal ---
__global__ __launch_bounds__(256) void k_bucket(const int* __restrict__ src,
                                                const int* __restrict__ dst,
                                                int* __restrict__ gfill,
                                                unsigned* __restrict__ pairs,
                                                int* __restrict__ offs) {
  __shared__ int bcnt[NB];
  __shared__ int brsv[NB];
  __shared__ int brank[NB];
  int t = threadIdx.x;
  if (blockIdx.x == 0 && t == 0) offs[N_NODES] = N_EDGES;
  for (int tile = blockIdx.x; tile < N_TILES; tile += gridDim.x) {
    int e0 = tile * TILE + t * EPT;
    for (int i = t; i < NB; i += 256) { bcnt[i] = 0; brank[i] = 0; }
    __syncthreads();
    int ds[EPT], ss[EPT];
    if (e0 + EPT <= N_EDGES) {
      *(int4*)&ds[0] = *(const int4*)&dst[e0];
      *(int4*)&ds[4] = *(const int4*)&dst[e0 + 4];
      *(int4*)&ss[0] = *(const int4*)&src[e0];
      *(int4*)&ss[4] = *(const int4*)&src[e0 + 4];
    } else {
      #pragma unroll
      for (int k = 0; k < EPT; ++k) {
        int e = e0 + k;
        ds[k] = (e < N_EDGES) ? dst[e] : -1;
        ss[k] = (e < N_EDGES) ? src[e] : 0;
      }
    }
    #pragma unroll
    for (int k = 0; k < EPT; ++k)
      if (ds[k] >= 0) atomicAdd(&bcnt[ds[k] >> BUCKET_SHIFT], 1);
    __syncthreads();
    for (int i = t; i < NB; i += 256) {
      int c = bcnt[i];
      brsv[i] = (c > 0) ? atomicAdd(&gfill[i], c) : 0;
    }
    __syncthreads();
    #pragma unroll
    for (int k = 0; k < EPT; ++k) {
      if (ds[k] >= 0) {
        int b = ds[k] >> BUCKET_SHIFT;
        int r = brsv[b] + atomicAdd(&brank[b], 1);
        if (r < CAP)
          pairs[(size_t)b * CAP + r] =
              ((unsigned)ss[k] << 8) | (unsigned)(ds[k] & (BUCKET_NODES - 1));
      }
    }
    __syncthreads();
  }
}

// ---------------- phase 2: per-bucket counting sort -> offs, ssrc -----------
// bbase computed inline: each block reduces gfill[0..b-1] itself.
__global__ __launch_bounds__(512) void k_localsort(const unsigned* __restrict__ pairs,
                                                   const int* __restrict__ gfill,
                                                   int* __restrict__ offs,
                                                   int* __restrict__ ssrc) {
  __shared__ int cnt_l[256];
  __shared__ int ss[256];
  __shared__ int cur_l[256];
  __shared__ int redsum[8];
  __shared__ int s_base;
  int b = blockIdx.x, t = threadIdx.x;
  // inline prefix: base = sum_{i<b} gfill[i]
  {
    int v = (t < NB && t < b) ? gfill[t] : 0;
    #pragma unroll
    for (int o = 32; o > 0; o >>= 1) v += __shfl_xor(v, o);
    if ((t & 63) == 0) redsum[t >> 6] = v;
  }
  if (t < 256) cnt_l[t] = 0;
  __syncthreads();
  if (t == 0) {
    int s = 0;
    #pragma unroll
    for (int i = 0; i < 8; ++i) s += redsum[i];
    s_base = s;
  }
  int E = min(gfill[b], CAP);
  const unsigned* pb = &pairs[(size_t)b * CAP];
  __syncthreads();
  int base = s_base;
  for (int i = t; i < E; i += 512)
    atomicAdd(&cnt_l[pb[i] & (BUCKET_NODES - 1)], 1);
  __syncthreads();
  if (t < 256) ss[t] = cnt_l[t];
  __syncthreads();
  #pragma unroll
  for (int d = 1; d < 256; d <<= 1) {
    int u = (t < 256 && t >= d) ? ss[t - d] : 0;
    __syncthreads();
    if (t < 256) ss[t] += u;
    __syncthreads();
  }
  if (t < 256) {
    int pre = (t == 0) ? 0 : ss[t - 1];
    int node = b * BUCKET_NODES + t;
    if (node < N_NODES) offs[node] = base + pre;
    cur_l[t] = pre;
  }
  __syncthreads();
  for (int i = t; i < E; i += 512) {
    unsigned p = pb[i];
    int pos = atomicAdd(&cur_l[p & (BUCKET_NODES - 1)], 1);
    ssrc[base + pos] = (int)(p >> 8);
  }
}

// ---------------- per-node softmax + weighted aggregation (bf16 ft) --------
// Half-wave (32 lanes) per node: softmax in one chunk for deg<=32
// (Poisson(16): P(deg>32) ~ 1e-4), chunked fallback otherwise.
#define AH_PAD 36
__global__ __launch_bounds__(256) void k_agg(const int* __restrict__ offs,
                                             const int* __restrict__ ssrc,
                                             const unsigned short* __restrict__ ftb,
                                             const float* __restrict__ el,
                                             const float* __restrict__ er,
                                             float* __restrict__ out) {
  __shared__ int   lds_s[4][2][32];
  __shared__ float lds_ah[4][2][4][AH_PAD];
  int wave = threadIdx.x >> 6;
  int lane = threadIdx.x & 63;
  int half = lane >> 5;
  int l32 = lane & 31;
  int n = blockIdx.x * 8 + wave * 2 + half;
  if (n >= N_NODES) return;
  int start = offs[n], end = offs[n + 1];
  int deg = end - start;

  int* sS = lds_s[wave][half];
  float (*sA)[AH_PAD] = lds_ah[wave][half];

  // aggregation lane roles: 4 cols per lane
  int c4 = l32 * 4;
  int hh = l32 >> 3;
  const unsigned short* fb = ftb + c4;
  float a0 = 0.f, a1 = 0.f, a2 = 0.f, a3 = 0.f;

  float4 er4 = *(const float4*)&er[n * 4];

  if (deg <= 32) {
    bool valid = l32 < deg;
    int s = valid ? ssrc[start + l32] : 0;
    float4 e4 = *(const float4*)&el[s * 4];
    float v[4] = {e4.x + er4.x, e4.y + er4.y, e4.z + er4.z, e4.w + er4.w};
    float m[4], ex[4], den[4];
    #pragma unroll
    for (int h = 0; h < 4; ++h) {
      v[h] = v[h] > 0.f ? v[h] : NEG_SLOPE * v[h];
      m[h] = valid ? v[h] : -INFINITY;
    }
    #pragma unroll
    for (int h = 0; h < 4; ++h)
      #pragma unroll
      for (int o = 16; o > 0; o >>= 1) m[h] = fmaxf(m[h], __shfl_xor(m[h], o));
    #pragma unroll
    for (int h = 0; h < 4; ++h) {
      ex[h] = valid ? __expf(v[h] - m[h]) : 0.f;
      den[h] = ex[h];
    }
    #pragma unroll
    for (int h = 0; h < 4; ++h)
      #pragma unroll
      for (int o = 16; o > 0; o >>= 1) den[h] += __shfl_xor(den[h], o);
    sS[l32] = s;
    #pragma unroll
    for (int h = 0; h < 4; ++h) sA[h][l32] = ex[h] / den[h];  // deg==0: NaN, never read
    __builtin_amdgcn_wave_barrier();
    for (int j = 0; j < deg; j += 4) {
      int4   sv = *(const int4*)&sS[j];
      float4 av = *(const float4*)&sA[hh][j];
      uint2 uA = *(const uint2*)&fb[(size_t)sv.x * D_HID];
      uint2 uB = *(const uint2*)&fb[(size_t)sv.y * D_HID];
      uint2 uC = *(const uint2*)&fb[(size_t)sv.z * D_HID];
      uint2 uD = *(const uint2*)&fb[(size_t)sv.w * D_HID];
      a0 += av.x * bfu_lo(uA.x); a1 += av.x * bfu_hi(uA.x);
      a2 += av.x * bfu_lo(uA.y); a3 += av.x * bfu_hi(uA.y);
      a0 += av.y * bfu_lo(uB.x); a1 += av.y * bfu_hi(uB.x);
      a2 += av.y * bfu_lo(uB.y); a3 += av.y * bfu_hi(uB.y);
      a0 += av.z * bfu_lo(uC.x); a1 += av.z * bfu_hi(uC.x);
      a2 += av.z * bfu_lo(uC.y); a3 += av.z * bfu_hi(uC.y);
      a0 += av.w * bfu_lo(uD.x); a1 += av.w * bfu_hi(uD.x);
      a2 += av.w * bfu_lo(uD.y); a3 += av.w * bfu_hi(uD.y);
    }
  } else {
    // ---- rare chunked path (deg > 32) ----
    float erh[4] = {er4.x, er4.y, er4.z, er4.w};
    float m[4] = {-INFINITY, -INFINITY, -INFINITY, -INFINITY};
    for (int c = start; c < end; c += 32) {
      int i = c + l32;
      bool valid = i < end;
      int s = valid ? ssrc[i] : 0;
      float4 e4 = *(const float4*)&el[s * 4];
      float ee[4] = {e4.x, e4.y, e4.z, e4.w};
      #pragma unroll
      for (int h = 0; h < 4; ++h) {
        float v = ee[h] + erh[h];
        v = v > 0.f ? v : NEG_SLOPE * v;
        m[h] = fmaxf(m[h], valid ? v : -INFINITY);
      }
    }
    #pragma unroll
    for (int h = 0; h < 4; ++h)
      #pragma unroll
      for (int o = 16; o > 0; o >>= 1) m[h] = fmaxf(m[h], __shfl_xor(m[h], o));
    float den[4] = {0.f, 0.f, 0.f, 0.f};
    for (int c = start; c < end; c += 32) {
      int i = c + l32;
      bool valid = i < end;
      int s = valid ? ssrc[i] : 0;
      float4 e4 = *(const float4*)&el[s * 4];
      float ee[4] = {e4.x, e4.y, e4.z, e4.w};
      #pragma unroll
      for (int h = 0; h < 4; ++h) {
        float v = ee[h] + erh[h];
        v = v > 0.f ? v : NEG_SLOPE * v;
        den[h] += valid ? __expf(v - m[h]) : 0.f;
      }
    }
    #pragma unroll
    for (int h = 0; h < 4; ++h)
      #pragma unroll
      for (int o = 16; o > 0; o >>= 1) den[h] += __shfl_xor(den[h], o);
    float invd[4];
    #pragma unroll
    for (int h = 0; h < 4; ++h) invd[h] = 1.f / den[h];
    for (int c = start; c < end; c += 32) {
      int i = c + l32;
      bool valid = i < end;
      int s = valid ? ssrc[i] : 0;
      float4 e4 = *(const float4*)&el[s * 4];
      float ee[4] = {e4.x, e4.y, e4.z, e4.w};
      float av[4];
      #pragma unroll
      for (int h = 0; h < 4; ++h) {
        float v = ee[h] + erh[h];
        v = v > 0.f ? v : NEG_SLOPE * v;
        av[h] = valid ? __expf(v - m[h]) * invd[h] : 0.f;
      }
      __builtin_amdgcn_wave_barrier();   // previous chunk's reads done
      sS[l32] = s;
      #pragma unroll
      for (int h = 0; h < 4; ++h) sA[h][l32] = av[h];
      __builtin_amdgcn_wave_barrier();
      int cnt = min(32, end - c);
      for (int j = 0; j < cnt; j += 4) {
        int4   sv = *(const int4*)&sS[j];
        float4 aw = *(const float4*)&sA[hh][j];
        uint2 uA = *(const uint2*)&fb[(size_t)sv.x * D_HID];
        uint2 uB = *(const uint2*)&fb[(size_t)sv.y * D_HID];
        uint2 uC = *(const uint2*)&fb[(size_t)sv.z * D_HID];
        uint2 uD = *(const uint2*)&fb[(size_t)sv.w * D_HID];
        a0 += aw.x * bfu_lo(uA.x); a1 += aw.x * bfu_hi(uA.x);
        a2 += aw.x * bfu_lo(uA.y); a3 += aw.x * bfu_hi(uA.y);
        a0 += aw.y * bfu_lo(uB.x); a1 += aw.y * bfu_hi(uB.x);
        a2 += aw.y * bfu_lo(uB.y); a3 += aw.y * bfu_hi(uB.y);
        a0 += aw.z * bfu_lo(uC.x); a1 += aw.z * bfu_hi(uC.x);
        a2 += aw.z * bfu_lo(uC.y); a3 += aw.z * bfu_hi(uC.y);
        a0 += aw.w * bfu_lo(uD.x); a1 += aw.w * bfu_hi(uD.x);
        a2 += aw.w * bfu_lo(uD.y); a3 += aw.w * bfu_hi(uD.y);
      }
    }
  }
  *(float4*)&out[(size_t)n * D_HID + c4] = make_float4(a0, a1, a2, a3);
}

extern "C" void kernel_launch(void* const* d_in, const int* in_sizes, int n_in,
                              void* d_out, int out_size, void* d_ws, size_t ws_size,
                              hipStream_t stream) {
  const float* x      = (const float*)d_in[0];
  const float* fc_w   = (const float*)d_in[1];
  const float* attn_l = (const float*)d_in[2];
  const float* attn_r = (const float*)d_in[3];
  const int*   src    = (const int*)d_in[4];
  const int*   dst    = (const int*)d_in[5];
  float* out = (float*)d_out;

  char* wsp = (char*)d_ws;
  size_t off = 0;
  auto alloc = [&](size_t bytes) {
    void* p = wsp + off;
    off = (off + bytes + 255) & ~(size_t)255;
    return p;
  };
  unsigned short* ftb = (unsigned short*)alloc((size_t)N_NODES * D_HID * 2);
  unsigned short* wb  = (unsigned short*)alloc((size_t)D_HID * D_IN * 2);
  float* el     = (float*)alloc((size_t)N_NODES * 4 * 4);
  float* er     = (float*)alloc((size_t)N_NODES * 4 * 4);
  int*   offs   = (int*)alloc((size_t)(N_NODES + 1) * 4);
  int*   ssrc   = (int*)alloc((size_t)N_EDGES * 4);
  int*   gfill  = (int*)alloc((size_t)NB * 4);
  unsigned* pairs = (unsigned*)alloc((size_t)NB * CAP * 4);

  hipMemsetAsync(gfill, 0, (size_t)NB * 4, stream);
  k_wcvt<<<(D_HID * D_IN / 4 + 255) / 256, 256, 0, stream>>>(fc_w, wb);
  k_gemm<<<(N_NODES + 127) / 128, 256, 0, stream>>>(x, wb, attn_l, attn_r, ftb, el, er);
  k_bucket<<<N_TILES, 256, 0, stream>>>(src, dst, gfill, pairs, offs);
  k_localsort<<<NB, 512, 0, stream>>>(pairs, gfill, offs, ssrc);
  k_agg<<<(N_NODES + 7) / 8, 256, 0, stream>>>(offs, ssrc, ftb, el, er, out);
}

// Round 7
// 313.708 us; speedup vs baseline: 1.1677x; 1.1677x over previous
//
#include <hip/hip_runtime.h>
#include <math.h>

#define N_NODES 100000
#define N_EDGES 1600000
#define D_IN 256
#define N_HEADS 4
#define D_OUT 32
#define D_HID 128   // N_HEADS*D_OUT
#define NEG_SLOPE 0.2f

// bucketed sort params
#define BUCKET_SHIFT 8
#define BUCKET_NODES 256
#define NB ((N_NODES + BUCKET_NODES - 1) / BUCKET_NODES)  // 391
#define CAP 6144      // >> mean 4096 + 32 sigma
#define TILE 2048
#define EPT 8         // edges per thread in k_bucket
#define N_TILES ((N_EDGES + TILE - 1) / TILE)             // 782

typedef __attribute__((ext_vector_type(8))) short bf16x8;
typedef __attribute__((ext_vector_type(4))) float f32x4;

// hardware packed f32->bf16 (RNE), 1 inst per 2 elements
static __device__ __forceinline__ unsigned cvt2(float lo, float hi) {
  unsigned r;
  asm("v_cvt_pk_bf16_f32 %0, %1, %2" : "=v"(r) : "v"(lo), "v"(hi));
  return r;
}
static __device__ __forceinline__ float bfu_lo(unsigned u) {
  union { unsigned u; float f; } c; c.u = u << 16; return c.f;
}
static __device__ __forceinline__ float bfu_hi(unsigned u) {
  union { unsigned u; float f; } c; c.u = u & 0xFFFF0000u; return c.f;
}

#define GL2LDS(g, l) \
  __builtin_amdgcn_global_load_lds( \
      (const __attribute__((address_space(1))) unsigned*)(g), \
      (__attribute__((address_space(3))) unsigned*)(l), 16, 0, 0)

// ---------------- w f32 -> bf16 pre-convert (64 KB, L2-resident) -----------
__global__ __launch_bounds__(256) void k_wcvt(const float* __restrict__ w,
                                              unsigned short* __restrict__ wb) {
  int i = blockIdx.x * 256 + threadIdx.x;   // float4 group index
  if (i < (D_HID * D_IN) / 4) {
    float4 v = ((const float4*)w)[i];
    ((uint2*)wb)[i] = make_uint2(cvt2(v.x, v.y), cvt2(v.z, v.w));
  }
}

// ---------------- GEMM: ftb[N,128](bf16) = x[N,256] @ w[128,256]^T ----------
// 2-phase pipeline with global_load_lds (fire-and-forget staging):
//   A: f32 x staged [128 rows x 32 f32] double-buffered, chunk-XOR swizzled
//      source (linear dest), XOR-read + cvt_pk to bf16 frags in regs.
//   B: bf16 wb staged [128 rows x 32 bf16] double-buffered, linear (already
//      bank-balanced).
// 48 KiB LDS -> 3 blocks/CU = 12 waves/CU. One barrier per K-step.
__global__ __launch_bounds__(256) void k_gemm(const float* __restrict__ x,
                                              const unsigned short* __restrict__ wb,
                                              const float* __restrict__ al,
                                              const float* __restrict__ ar,
                                              unsigned short* __restrict__ ftb,
                                              float* __restrict__ el,
                                              float* __restrict__ er) {
  __shared__ uint4 AsU[2][1024];   // 2 x 16384 B : [128][32] f32
  __shared__ uint4 BsU[2][512];    // 2 x  8192 B : [128][32] bf16
  int t = threadIdx.x;
  int wave = t >> 6, lane = t & 63;
  int quad = lane >> 4, l16 = lane & 15;
  int rowBlk = blockIdx.x * 128;

  // ---- staging geometry (per wave: 4 A-instrs, 2 B-instrs) ----
  // A instr i: dest = As + wave*4096 + i*1024; lane covers row
  //   wave*32 + i*8 + (lane>>3), chunk (lane&7) of 8x16B; source chunk
  //   pre-swizzled by XOR (lane>>3) so XOR-read is conflict-balanced.
  int arowL = wave * 32 + (lane >> 3);            // + i*8
  int aswz  = ((lane & 7) ^ (lane >> 3)) * 16;    // source byte-in-row
  // B instr i: dest = Bs + wave*2048 + i*1024; row wave*32+i*16+(lane>>2),
  //   chunk lane&3 (linear).
  int browL = wave * 32 + (lane >> 2);            // + i*16
  int brem  = (lane & 3) * 16;

  f32x4 acc[2][8];
  #pragma unroll
  for (int mt = 0; mt < 2; ++mt)
    #pragma unroll
    for (int nt = 0; nt < 8; ++nt) {
      acc[mt][nt][0] = 0.f; acc[mt][nt][1] = 0.f;
      acc[mt][nt][2] = 0.f; acc[mt][nt][3] = 0.f;
    }

  const char* xB  = (const char*)x;
  const char* wbB = (const char*)wb;

  #define STAGE(buf, tt) do {                                              \
    int kA = (tt) * 128;                                                   \
    int kB = (tt) * 64;                                                    \
    _Pragma("unroll")                                                      \
    for (int i = 0; i < 4; ++i) {                                          \
      int grow = rowBlk + arowL + i * 8;                                   \
      if (grow >= N_NODES) grow = N_NODES - 1;                             \
      GL2LDS(xB + (size_t)grow * 1024 + kA + aswz,                         \
             (char*)&AsU[buf][0] + wave * 4096 + i * 1024);                \
    }                                                                      \
    _Pragma("unroll")                                                      \
    for (int i = 0; i < 2; ++i) {                                          \
      int brw = browL + i * 16;                                            \
      GL2LDS(wbB + (size_t)brw * 512 + kB + brem,                          \
             (char*)&BsU[buf][0] + wave * 2048 + i * 1024);                \
    }                                                                      \
  } while (0)

  STAGE(0, 0);
  __syncthreads();

  int rA = wave * 32 + l16;
  int sA = l16 & 7;                 // A read chunk-XOR
  #pragma unroll
  for (int tt = 0; tt < 8; ++tt) {
    int cur = tt & 1;
    if (tt < 7) STAGE(cur ^ 1, tt + 1);
    const char* Ab = (const char*)&AsU[cur][0];
    const char* Bb = (const char*)&BsU[cur][0];
    // A frags: rows rA, rA+16; f32 chunks (quad*2)^sA and (quad*2+1)^sA
    float4 fa00 = *(const float4*)(Ab + rA * 128 + (((quad * 2)     ^ sA) << 4));
    float4 fa01 = *(const float4*)(Ab + rA * 128 + (((quad * 2 + 1) ^ sA) << 4));
    float4 fa10 = *(const float4*)(Ab + (rA + 16) * 128 + (((quad * 2)     ^ sA) << 4));
    float4 fa11 = *(const float4*)(Ab + (rA + 16) * 128 + (((quad * 2 + 1) ^ sA) << 4));
    bf16x8 bfr[8];
    #pragma unroll
    for (int nt = 0; nt < 8; ++nt)
      bfr[nt] = *(const bf16x8*)(Bb + (nt * 16 + l16) * 64 + quad * 16);
    union { unsigned u[4]; bf16x8 v; } a0c, a1c;
    a0c.u[0] = cvt2(fa00.x, fa00.y); a0c.u[1] = cvt2(fa00.z, fa00.w);
    a0c.u[2] = cvt2(fa01.x, fa01.y); a0c.u[3] = cvt2(fa01.z, fa01.w);
    a1c.u[0] = cvt2(fa10.x, fa10.y); a1c.u[1] = cvt2(fa10.z, fa10.w);
    a1c.u[2] = cvt2(fa11.x, fa11.y); a1c.u[3] = cvt2(fa11.z, fa11.w);
    #pragma unroll
    for (int nt = 0; nt < 8; ++nt) {
      acc[0][nt] = __builtin_amdgcn_mfma_f32_16x16x32_bf16(a0c.v, bfr[nt], acc[0][nt], 0, 0, 0);
      acc[1][nt] = __builtin_amdgcn_mfma_f32_16x16x32_bf16(a1c.v, bfr[nt], acc[1][nt], 0, 0, 0);
    }
    __syncthreads();
  }
  #undef STAGE

  int rowBase = rowBlk + wave * 32;

  // ftb store (bf16)
  #pragma unroll
  for (int mt = 0; mt < 2; ++mt) {
    #pragma unroll
    for (int nt = 0; nt < 8; ++nt) {
      int col = nt * 16 + l16;
      #pragma unroll
      for (int r = 0; r < 4; r += 2) {
        unsigned p = cvt2(acc[mt][nt][r], acc[mt][nt][r + 1]);
        int row = rowBase + mt * 16 + quad * 4 + r;
        if (row < N_NODES)
          ftb[(size_t)row * D_HID + col] = (unsigned short)p;
        if (row + 1 < N_NODES)
          ftb[(size_t)(row + 1) * D_HID + col] = (unsigned short)(p >> 16);
      }
    }
  }

  // fused el/er from f32 accumulators: head h covers nt {2h, 2h+1};
  // reduce over the 16 lanes of the quad.
  float alf[8], arf[8];
  #pragma unroll
  for (int nt = 0; nt < 8; ++nt) {
    alf[nt] = al[nt * 16 + l16];
    arf[nt] = ar[nt * 16 + l16];
  }
  #pragma unroll
  for (int mt = 0; mt < 2; ++mt) {
    #pragma unroll
    for (int r = 0; r < 4; ++r) {
      int row = rowBase + mt * 16 + quad * 4 + r;
      float sl[4], sr[4];
      #pragma unroll
      for (int h = 0; h < 4; ++h) {
        sl[h] = acc[mt][2 * h][r] * alf[2 * h] + acc[mt][2 * h + 1][r] * alf[2 * h + 1];
        sr[h] = acc[mt][2 * h][r] * arf[2 * h] + acc[mt][2 * h + 1][r] * arf[2 * h + 1];
      }
      #pragma unroll
      for (int o = 1; o < 16; o <<= 1) {
        #pragma unroll
        for (int h = 0; h < 4; ++h) {
          sl[h] += __shfl_xor(sl[h], o);
          sr[h] += __shfl_xor(sr[h], o);
        }
      }
      if (l16 == 0 && row < N_NODES) {
        *(float4*)&el[row * 4] = make_float4(sl[0], sl[1], sl[2], sl[3]);
        *(float4*)&er[row * 4] = make_float4(sr[0], sr[1], sr[2], sr[3]);
      }
    }
  }
}

// ---------------- phase 1: bucket edges by dst>>8, packed (src<<8)|dlocal ---
__global__ __launch_bounds__(256) void k_bucket(const int* __restrict__ src,
                                                const int* __restrict__ dst,
                                                int* __restrict__ gfill,
                                                unsigned* __restrict__ pairs,
                                                int* __restrict__ offs) {
  __shared__ int bcnt[NB];
  __shared__ int brsv[NB];
  __shared__ int brank[NB];
  int t = threadIdx.x;
  if (blockIdx.x == 0 && t == 0) offs[N_NODES] = N_EDGES;
  for (int tile = blockIdx.x; tile < N_TILES; tile += gridDim.x) {
    int e0 = tile * TILE + t * EPT;
    for (int i = t; i < NB; i += 256) { bcnt[i] = 0; brank[i] = 0; }
    __syncthreads();
    int ds[EPT], ss[EPT];
    if (e0 + EPT <= N_EDGES) {
      *(int4*)&ds[0] = *(const int4*)&dst[e0];
      *(int4*)&ds[4] = *(const int4*)&dst[e0 + 4];
      *(int4*)&ss[0] = *(const int4*)&src[e0];
      *(int4*)&ss[4] = *(const int4*)&src[e0 + 4];
    } else {
      #pragma unroll
      for (int k = 0; k < EPT; ++k) {
        int e = e0 + k;
        ds[k] = (e < N_EDGES) ? dst[e] : -1;
        ss[k] = (e < N_EDGES) ? src[e] : 0;
      }
    }
    #pragma unroll
    for (int k = 0; k < EPT; ++k)
      if (ds[k] >= 0) atomicAdd(&bcnt[ds[k] >> BUCKET_SHIFT], 1);
    __syncthreads();
    for (int i = t; i < NB; i += 256) {
      int c = bcnt[i];
      brsv[i] = (c > 0) ? atomicAdd(&gfill[i], c) : 0;
    }
    __syncthreads();
    #pragma unroll
    for (int k = 0; k < EPT; ++k) {
      if (ds[k] >= 0) {
        int b = ds[k] >> BUCKET_SHIFT;
        int r = brsv[b] + atomicAdd(&brank[b], 1);
        if (r < CAP)
          pairs[(size_t)b * CAP + r] =
              ((unsigned)ss[k] << 8) | (unsigned)(ds[k] & (BUCKET_NODES - 1));
      }
    }
    __syncthreads();
  }
}

// ---------------- phase 2: per-bucket counting sort -> offs, ssrc -----------
// bbase computed inline: each block reduces gfill[0..b-1] itself.
__global__ __launch_bounds__(512) void k_localsort(const unsigned* __restrict__ pairs,
                                                   const int* __restrict__ gfill,
                                                   int* __restrict__ offs,
                                                   int* __restrict__ ssrc) {
  __shared__ int cnt_l[256];
  __shared__ int ss[256];
  __shared__ int cur_l[256];
  __shared__ int redsum[8];
  __shared__ int s_base;
  int b = blockIdx.x, t = threadIdx.x;
  // inline prefix: base = sum_{i<b} gfill[i]
  {
    int v = (t < NB && t < b) ? gfill[t] : 0;
    #pragma unroll
    for (int o = 32; o > 0; o >>= 1) v += __shfl_xor(v, o);
    if ((t & 63) == 0) redsum[t >> 6] = v;
  }
  if (t < 256) cnt_l[t] = 0;
  __syncthreads();
  if (t == 0) {
    int s = 0;
    #pragma unroll
    for (int i = 0; i < 8; ++i) s += redsum[i];
    s_base = s;
  }
  int E = min(gfill[b], CAP);
  const unsigned* pb = &pairs[(size_t)b * CAP];
  __syncthreads();
  int base = s_base;
  for (int i = t; i < E; i += 512)
    atomicAdd(&cnt_l[pb[i] & (BUCKET_NODES - 1)], 1);
  __syncthreads();
  if (t < 256) ss[t] = cnt_l[t];
  __syncthreads();
  #pragma unroll
  for (int d = 1; d < 256; d <<= 1) {
    int u = (t < 256 && t >= d) ? ss[t - d] : 0;
    __syncthreads();
    if (t < 256) ss[t] += u;
    __syncthreads();
  }
  if (t < 256) {
    int pre = (t == 0) ? 0 : ss[t - 1];
    int node = b * BUCKET_NODES + t;
    if (node < N_NODES) offs[node] = base + pre;
    cur_l[t] = pre;
  }
  __syncthreads();
  for (int i = t; i < E; i += 512) {
    unsigned p = pb[i];
    int pos = atomicAdd(&cur_l[p & (BUCKET_NODES - 1)], 1);
    ssrc[base + pos] = (int)(p >> 8);
  }
}

// ---------------- per-node softmax + weighted aggregation (bf16 ft) --------
// Half-wave (32 lanes) per node: softmax in one chunk for deg<=32
// (Poisson(16): P(deg>32) ~ 1e-4), chunked fallback otherwise.
#define AH_PAD 36
__global__ __launch_bounds__(256) void k_agg(const int* __restrict__ offs,
                                             const int* __restrict__ ssrc,
                                             const unsigned short* __restrict__ ftb,
                                             const float* __restrict__ el,
                                             const float* __restrict__ er,
                                             float* __restrict__ out) {
  __shared__ int   lds_s[4][2][32];
  __shared__ float lds_ah[4][2][4][AH_PAD];
  int wave = threadIdx.x >> 6;
  int lane = threadIdx.x & 63;
  int half = lane >> 5;
  int l32 = lane & 31;
  int n = blockIdx.x * 8 + wave * 2 + half;
  if (n >= N_NODES) return;
  int start = offs[n], end = offs[n + 1];
  int deg = end - start;

  int* sS = lds_s[wave][half];
  float (*sA)[AH_PAD] = lds_ah[wave][half];

  // aggregation lane roles: 4 cols per lane
  int c4 = l32 * 4;
  int hh = l32 >> 3;
  const unsigned short* fb = ftb + c4;
  float a0 = 0.f, a1 = 0.f, a2 = 0.f, a3 = 0.f;

  float4 er4 = *(const float4*)&er[n * 4];

  if (deg <= 32) {
    bool valid = l32 < deg;
    int s = valid ? ssrc[start + l32] : 0;
    float4 e4 = *(const float4*)&el[s * 4];
    float v[4] = {e4.x + er4.x, e4.y + er4.y, e4.z + er4.z, e4.w + er4.w};
    float m[4], ex[4], den[4];
    #pragma unroll
    for (int h = 0; h < 4; ++h) {
      v[h] = v[h] > 0.f ? v[h] : NEG_SLOPE * v[h];
      m[h] = valid ? v[h] : -INFINITY;
    }
    #pragma unroll
    for (int h = 0; h < 4; ++h)
      #pragma unroll
      for (int o = 16; o > 0; o >>= 1) m[h] = fmaxf(m[h], __shfl_xor(m[h], o));
    #pragma unroll
    for (int h = 0; h < 4; ++h) {
      ex[h] = valid ? __expf(v[h] - m[h]) : 0.f;
      den[h] = ex[h];
    }
    #pragma unroll
    for (int h = 0; h < 4; ++h)
      #pragma unroll
      for (int o = 16; o > 0; o >>= 1) den[h] += __shfl_xor(den[h], o);
    sS[l32] = s;
    #pragma unroll
    for (int h = 0; h < 4; ++h) sA[h][l32] = ex[h] / den[h];  // deg==0: NaN, never read
    __builtin_amdgcn_wave_barrier();
    for (int j = 0; j < deg; j += 4) {
      int4   sv = *(const int4*)&sS[j];
      float4 av = *(const float4*)&sA[hh][j];
      uint2 uA = *(const uint2*)&fb[(size_t)sv.x * D_HID];
      uint2 uB = *(const uint2*)&fb[(size_t)sv.y * D_HID];
      uint2 uC = *(const uint2*)&fb[(size_t)sv.z * D_HID];
      uint2 uD = *(const uint2*)&fb[(size_t)sv.w * D_HID];
      a0 += av.x * bfu_lo(uA.x); a1 += av.x * bfu_hi(uA.x);
      a2 += av.x * bfu_lo(uA.y); a3 += av.x * bfu_hi(uA.y);
      a0 += av.y * bfu_lo(uB.x); a1 += av.y * bfu_hi(uB.x);
      a2 += av.y * bfu_lo(uB.y); a3 += av.y * bfu_hi(uB.y);
      a0 += av.z * bfu_lo(uC.x); a1 += av.z * bfu_hi(uC.x);
      a2 += av.z * bfu_lo(uC.y); a3 += av.z * bfu_hi(uC.y);
      a0 += av.w * bfu_lo(uD.x); a1 += av.w * bfu_hi(uD.x);
      a2 += av.w * bfu_lo(uD.y); a3 += av.w * bfu_hi(uD.y);
    }
  } else {
    // ---- rare chunked path (deg > 32) ----
    float erh[4] = {er4.x, er4.y, er4.z, er4.w};
    float m[4] = {-INFINITY, -INFINITY, -INFINITY, -INFINITY};
    for (int c = start; c < end; c += 32) {
      int i = c + l32;
      bool valid = i < end;
      int s = valid ? ssrc[i] : 0;
      float4 e4 = *(const float4*)&el[s * 4];
      float ee[4] = {e4.x, e4.y, e4.z, e4.w};
      #pragma unroll
      for (int h = 0; h < 4; ++h) {
        float v = ee[h] + erh[h];
        v = v > 0.f ? v : NEG_SLOPE * v;
        m[h] = fmaxf(m[h], valid ? v : -INFINITY);
      }
    }
    #pragma unroll
    for (int h = 0; h < 4; ++h)
      #pragma unroll
      for (int o = 16; o > 0; o >>= 1) m[h] = fmaxf(m[h], __shfl_xor(m[h], o));
    float den[4] = {0.f, 0.f, 0.f, 0.f};
    for (int c = start; c < end; c += 32) {
      int i = c + l32;
      bool valid = i < end;
      int s = valid ? ssrc[i] : 0;
      float4 e4 = *(const float4*)&el[s * 4];
      float ee[4] = {e4.x, e4.y, e4.z, e4.w};
      #pragma unroll
      for (int h = 0; h < 4; ++h) {
        float v = ee[h] + erh[h];
        v = v > 0.f ? v : NEG_SLOPE * v;
        den[h] += valid ? __expf(v - m[h]) : 0.f;
      }
    }
    #pragma unroll
    for (int h = 0; h < 4; ++h)
      #pragma unroll
      for (int o = 16; o > 0; o >>= 1) den[h] += __shfl_xor(den[h], o);
    float invd[4];
    #pragma unroll
    for (int h = 0; h < 4; ++h) invd[h] = 1.f / den[h];
    for (int c = start; c < end; c += 32) {
      int i = c + l32;
      bool valid = i < end;
      int s = valid ? ssrc[i] : 0;
      float4 e4 = *(const float4*)&el[s * 4];
      float ee[4] = {e4.x, e4.y, e4.z, e4.w};
      float av[4];
      #pragma unroll
      for (int h = 0; h < 4; ++h) {
        float v = ee[h] + erh[h];
        v = v > 0.f ? v : NEG_SLOPE * v;
        av[h] = valid ? __expf(v - m[h]) * invd[h] : 0.f;
      }
      __builtin_amdgcn_wave_barrier();   // previous chunk's reads done
      sS[l32] = s;
      #pragma unroll
      for (int h = 0; h < 4; ++h) sA[h][l32] = av[h];
      __builtin_amdgcn_wave_barrier();
      int cnt = min(32, end - c);
      for (int j = 0; j < cnt; j += 4) {
        int4   sv = *(const int4*)&sS[j];
        float4 aw = *(const float4*)&sA[hh][j];
        uint2 uA = *(const uint2*)&fb[(size_t)sv.x * D_HID];
        uint2 uB = *(const uint2*)&fb[(size_t)sv.y * D_HID];
        uint2 uC = *(const uint2*)&fb[(size_t)sv.z * D_HID];
        uint2 uD = *(const uint2*)&fb[(size_t)sv.w * D_HID];
        a0 += aw.x * bfu_lo(uA.x); a1 += aw.x * bfu_hi(uA.x);
        a2 += aw.x * bfu_lo(uA.y); a3 += aw.x * bfu_hi(uA.y);
        a0 += aw.y * bfu_lo(uB.x); a1 += aw.y * bfu_hi(uB.x);
        a2 += aw.y * bfu_lo(uB.y); a3 += aw.y * bfu_hi(uB.y);
        a0 += aw.z * bfu_lo(uC.x); a1 += aw.z * bfu_hi(uC.x);
        a2 += aw.z * bfu_lo(uC.y); a3 += aw.z * bfu_hi(uC.y);
        a0 += aw.w * bfu_lo(uD.x); a1 += aw.w * bfu_hi(uD.x);
        a2 += aw.w * bfu_lo(uD.y); a3 += aw.w * bfu_hi(uD.y);
      }
    }
  }
  *(float4*)&out[(size_t)n * D_HID + c4] = make_float4(a0, a1, a2, a3);
}

extern "C" void kernel_launch(void* const* d_in, const int* in_sizes, int n_in,
                              void* d_out, int out_size, void* d_ws, size_t ws_size,
                              hipStream_t stream) {
  const float* x      = (const float*)d_in[0];
  const float* fc_w   = (const float*)d_in[1];
  const float* attn_l = (const float*)d_in[2];
  const float* attn_r = (const float*)d_in[3];
  const int*   src    = (const int*)d_in[4];
  const int*   dst    = (const int*)d_in[5];
  float* out = (float*)d_out;

  char* wsp = (char*)d_ws;
  size_t off = 0;
  auto alloc = [&](size_t bytes) {
    void* p = wsp + off;
    off = (off + bytes + 255) & ~(size_t)255;
    return p;
  };
  unsigned short* ftb = (unsigned short*)alloc((size_t)N_NODES * D_HID * 2);
  unsigned short* wb  = (unsigned short*)alloc((size_t)D_HID * D_IN * 2);
  float* el     = (float*)alloc((size_t)N_NODES * 4 * 4);
  float* er     = (float*)alloc((size_t)N_NODES * 4 * 4);
  int*   offs   = (int*)alloc((size_t)(N_NODES + 1) * 4);
  int*   ssrc   = (int*)alloc((size_t)N_EDGES * 4);
  int*   gfill  = (int*)alloc((size_t)NB * 4);
  unsigned* pairs = (unsigned*)alloc((size_t)NB * CAP * 4);

  hipMemsetAsync(gfill, 0, (size_t)NB * 4, stream);
  k_wcvt<<<(D_HID * D_IN / 4 + 255) / 256, 256, 0, stream>>>(fc_w, wb);
  k_gemm<<<(N_NODES + 127) / 128, 256, 0, stream>>>(x, wb, attn_l, attn_r, ftb, el, er);
  k_bucket<<<N_TILES, 256, 0, stream>>>(src, dst, gfill, pairs, offs);
  k_localsort<<<NB, 512, 0, stream>>>(pairs, gfill, offs, ssrc);
  k_agg<<<(N_NODES + 7) / 8, 256, 0, stream>>>(offs, ssrc, ftb, el, er, out);
}